// Round 8
// baseline (204.647 us; speedup 1.0000x reference)
//
#include <hip/hip_runtime.h>
#include <cstdint>

#define NPRED 25200      // total predictions (8400 positions * 3 anchors)
#define NPOS  8400
#define NCLS  80
#define CAP   512        // max boxes per class (mean ~315, sigma ~18)
#define MW    8          // u64 mask words per row (512/64)
#define NCHUNK 132       // 64-position chunks: 100 (s0) + 25 (s1) + 7 (s2 tail)

__device__ __forceinline__ float sigmoidf_(float x) { return 1.0f / (1.0f + expf(-x)); }

// Block = (64-position chunk, anchor), 64 threads. 80 class logits staged to
// LDS via TWO-PHASE float4 loads. argmax(softmax*obj) == argmax(e) since
// /s and *obj are positive monotone maps -> pass B fuses sum+argmax (strict
// > ascending on e == ref's first-max rule); final best = beste/s*obj is the
// ref expression at the argmax index (bit-identical value). Emits dense
// class-tagged key g_key[g] (cls[53:47]|score[46:15]|g[14:0]; cls=127
// sentinel) + offset box.
__global__ __launch_bounds__(64) void decode_kernel(
    const float* __restrict__ ps, const float* __restrict__ pm, const float* __restrict__ pl,
    float* __restrict__ out,
    float4* __restrict__ g_boxin, uint64_t* __restrict__ g_key)
{
    int chunk = blockIdx.x;
    int a     = blockIdx.y;
    int t     = threadIdx.x;

    const float* p; int HW, W, base, si; float stride; int w0;
    if (chunk < 100)      { p = ps; HW = 6400; W = 80; stride = 8.f;  base = 0;    si = 0; w0 = chunk * 64; }
    else if (chunk < 125) { p = pm; HW = 1600; W = 40; stride = 16.f; base = 6400; si = 1; w0 = (chunk - 100) * 64; }
    else                  { p = pl; HW = 400;  W = 20; stride = 32.f; base = 8000; si = 2; w0 = (chunk - 125) * 64; }

    int local = w0 + t;
    bool valid = local < HW;
    int lclamp = valid ? local : (HW - 1);

    __shared__ float lds[NCLS * 64];          // 20 KB

    const float* cbase = p + (size_t)(3 + a * NCLS) * HW;
    int lane_c = t >> 4;                      // 0..3
    int j      = (t & 15) << 2;               // 0,4,...,60
    int off    = w0 + j; if (off > HW - 4) off = HW - 4;   // tail clamp

    // phase 1: all 20 loads in flight
    float4 vreg[20];
#pragma unroll
    for (int r0 = 0; r0 < 20; r0++)
        vreg[r0] = *(const float4*)(cbase + (size_t)(r0 * 4 + lane_c) * HW + off);
    // small per-thread loads join the same wait group
    float objl = p[(size_t)a * HW + lclamp];
    const float* rb = p + (size_t)(3 + 3 * NCLS + a * 4) * HW + lclamp;
    float tx = rb[0], ty = rb[(size_t)HW], tw = rb[(size_t)2 * HW], th = rb[(size_t)3 * HW];
    // phase 2: LDS writes
#pragma unroll
    for (int r0 = 0; r0 < 20; r0++)
        *(float4*)&lds[(r0 * 4 + lane_c) * 64 + j] = vreg[r0];
    __syncthreads();

    // pass A: max (ascending, order-exact)
    float m = -INFINITY;
#pragma unroll 16
    for (int c = 0; c < NCLS; c++) m = fmaxf(m, lds[c * 64 + t]);
    // pass B: serial ascending sum + argmax of e (strict >, ascending ==
    // jnp.argmax first-max; monotone e->e/s*obj preserves order/value)
    float s = 0.f; float beste = -1.f; int bi = 0;
#pragma unroll 16
    for (int c = 0; c < NCLS; c++) {
        float e = expf(lds[c * 64 + t] - m);
        s += e;
        if (e > beste) { beste = e; bi = c; }
    }
    float obj = sigmoidf_(objl);
    float best = beste / s * obj;             // == ref's (e/s)*obj at argmax

    if (!valid) return;

    const float AW[9] = {10.f,16.f,33.f, 30.f,62.f,59.f, 116.f,156.f,373.f};
    const float AH[9] = {13.f,30.f,23.f, 61.f,45.f,119.f, 90.f,198.f,326.f};
    float aw = AW[si*3 + a], ah = AH[si*3 + a];

    int y = local / W;
    int x = local - y * W;
    float cx = (sigmoidf_(tx) + (float)x) * stride;
    float cy = (sigmoidf_(ty) + (float)y) * stride;
    float bw = expf(tw) * aw;
    float bh = expf(th) * ah;
    float x1 = fminf(fmaxf((cx - bw / 2.f) / 640.f, 0.f), 1.f);
    float y1 = fminf(fmaxf((cy - bh / 2.f) / 640.f, 0.f), 1.f);
    float x2 = fminf(fmaxf((cx + bw / 2.f) / 640.f, 0.f), 1.f);
    float y2 = fminf(fmaxf((cy + bh / 2.f) / 640.f, 0.f), 1.f);

    int g = (base + local) * 3 + a;           // reference global ordering
    float clsf = (float)bi;
    float* o = out + (size_t)g * 7;
    o[0] = x1; o[1] = y1; o[2] = x2; o[3] = y2;
    o[4] = best; o[5] = clsf; o[6] = 0.f;

    if (best >= 0.001f) {
        float off2 = clsf * 2.0f;             // ref IoU uses class-offset boxes
        g_boxin[g] = make_float4(x1 + off2, y1 + off2, x2 + off2, y2 + off2);
        unsigned u = __float_as_uint(best);
        u = (u & 0x80000000u) ? ~u : (u | 0x80000000u);
        g_key[g] = ((uint64_t)bi << 47) | ((uint64_t)(~u) << 15) | (uint64_t)g;
    } else {
        g_key[g] = (uint64_t)127 << 47;       // sentinel class: never matched
    }
}

// ============================================================================
// PROBE kernel (diagnostic ablation): same code as nms_fused_kernel but with a
// runtime-uniform `phases` truncation arg; writes ONLY to a scratch region.
// Runtime branches -> identical codegen across variants, zero DCE risk.
// Per-dispatch rocprof durations attribute the 41us across phases:
//   phases=-1 floor | 0 +bucket/gather | 1 +sort | 2 +build | 3 full
// ============================================================================
__global__ __launch_bounds__(1024, 4) void nms_probe_kernel(
    const uint64_t* __restrict__ g_key, const float4* __restrict__ g_boxin,
    float* __restrict__ dummy, int phases)
{
    int c = blockIdx.x;
    int tid = threadIdx.x;

    uint64_t* d64 = (uint64_t*)dummy;                 // 8 KB region
    float4*   d4  = (float4*)(dummy + 4096);          // 8 KB region
    int*      di  = (int*)(dummy + 8192);             // 2 KB region
    float*    dk  = dummy + 16384;                    // keep-flag region (100 KB)

    __shared__ uint64_t key_s[CAP];
    __shared__ float4   boxu_s[CAP];
    __shared__ float4   sbox_s[CAP + 64];
    __shared__ int      sg_s[CAP];
    __shared__ uint64_t mask_s[MW * CAP];
    __shared__ int      ln_s;

    if (phases < 0) {                         // floor: launch + LDS-alloc + 2 reads
        uint64_t v = g_key[tid] + g_key[NPRED - 1 - tid];
        if (c == 0) d64[tid & 1023] = v;
        return;
    }

    if (tid == 0) ln_s = 0;
    __syncthreads();

    // ---- phase 0: bucket class-c keys
    {
        int lane = tid & 63;
        const ulonglong2* kp = (const ulonglong2*)g_key;
        for (int idx = tid; idx < NPRED / 2; idx += 1024) {
            ulonglong2 kv = kp[idx];
            bool m0 = (int)(kv.x >> 47) == c;
            bool m1 = (int)(kv.y >> 47) == c;
            unsigned long long b0 = __ballot(m0);
            unsigned long long b1 = __ballot(m1);
            int total = __popcll(b0) + __popcll(b1);
            int base = 0;
            if (lane == 0 && total) base = atomicAdd(&ln_s, total);
            base = __shfl(base, 0);
            unsigned long long lower = ((unsigned long long)1 << lane) - 1;
            int off0 = base + __popcll(b0 & lower);
            int off1 = base + __popcll(b0) + __popcll(b1 & lower);
            if (m0 && off0 < CAP) key_s[off0] = kv.x;
            if (m1 && off1 < CAP) key_s[off1] = kv.y;
        }
    }
    __syncthreads();
    int n = ln_s; if (n > CAP) n = CAP;
    if (n == 0) return;
    int nw = (n + 63) >> 6;

    for (int i = tid; i < n; i += 1024)
        boxu_s[i] = g_boxin[key_s[i] & 0x7FFF];
    for (int i = n + tid; i < n + 64; i += 1024)
        sbox_s[i] = make_float4(3e30f, 3e30f, 3e30f, 3e30f);
    __syncthreads();

    if (phases == 0) {                        // dump bucket+gather state, exit
        if (c == 0 && tid < CAP) { d64[tid] = key_s[tid]; d4[tid] = boxu_s[tid]; }
        return;
    }

    // ---- sort
    for (int i0 = 0; i0 < n; i0 += 256) {
        int item = i0 + (tid >> 2);
        int sub  = tid & 3;
        bool act = item < n;
        int r = 0;
        uint64_t k = 0;
        if (act) {
            k = key_s[item];
            int nq = (n + 3) >> 2;
            int lo = sub * nq; if (lo > n) lo = n;
            int hi = lo + nq;  if (hi > n) hi = n;
            int jj = lo;
            for (; jj + 8 <= hi; jj += 8) {
                int t0 = key_s[jj]   < k, t1 = key_s[jj+1] < k;
                int t2 = key_s[jj+2] < k, t3 = key_s[jj+3] < k;
                int t4 = key_s[jj+4] < k, t5 = key_s[jj+5] < k;
                int t6 = key_s[jj+6] < k, t7 = key_s[jj+7] < k;
                r += t0 + t1 + t2 + t3 + t4 + t5 + t6 + t7;
            }
            for (; jj < hi; jj++) r += (key_s[jj] < k);
        }
        r += __shfl_xor(r, 1);
        r += __shfl_xor(r, 2);
        if (act && sub == 0) {
            sbox_s[r] = boxu_s[item];
            sg_s[r]   = (int)(k & 0x7FFF);
        }
    }
    __syncthreads();

    if (phases == 1) {                        // dump sorted state, exit
        if (c == 0 && tid < CAP) { d4[tid] = sbox_s[tid]; di[tid] = sg_s[tid]; }
        return;
    }

    // ---- build
    {
        int wid   = tid >> 6;
        int lane2 = tid & 63;
        int T = nw * (nw + 1) / 2;
        for (int t = wid; t < T; t += 16) {
            int w = 0, acc = 0;
            while (t >= acc + w + 1) { acc += w + 1; w++; }
            int ib = t - acc;
            int i  = (ib << 6) + lane2;
            float4 b4 = sbox_s[i];
            float Ai = (b4.z - b4.x) * (b4.w - b4.y);
            int j0 = w << 6;
            uint64_t bits = 0;
#pragma unroll 8
            for (int jq = 0; jq < 64; jq++) {
                float4 bj = sbox_s[j0 + jq];
                float xx1 = fmaxf(b4.x, bj.x);
                float yy1 = fmaxf(b4.y, bj.y);
                float xx2 = fminf(b4.z, bj.z);
                float yy2 = fminf(b4.w, bj.w);
                float ww = fmaxf(1e-28f, xx2 - xx1);
                float hh = fmaxf(1e-28f, yy2 - yy1);
                float inter = ww * hh;
                float Aj = (bj.z - bj.x) * (bj.w - bj.y);
                float iou = inter / ((Ai + Aj) - inter);
                if ((j0 + jq) > i && iou > 0.6f) bits |= 1ull << jq;
            }
            if (i < n) mask_s[w * CAP + i] = bits;
        }
    }
    __syncthreads();

    if (phases == 2) {                        // XOR-reduce mask (keeps build live)
        uint64_t x = 0;
        for (int i = tid; i < MW * CAP; i += 1024) x ^= mask_s[i];
        if (c == 0) d64[tid] = x;
        return;
    }

    // ---- scan (full) -> keep flags into dummy region
    if (tid >= 64) return;
    int lane = tid;
    uint64_t removed = 0;
    for (int w = 0; w < nw; w++) {
        uint64_t rw = __shfl(removed, w);
        int row = (w << 6) + lane;
        uint64_t diag = (row < n) ? mask_s[w * CAP + row] : 0ull;
        int rem = n - (w << 6);
        uint64_t valid = (rem >= 64) ? ~0ull : ((1ull << rem) - 1ull);
        uint64_t nulls = __ballot(diag == 0ull);
        uint64_t cand = ~rw & valid;
        uint64_t kw = 0;
        uint64_t it = cand & ~nulls;
        while (it) {
            int b = __ffsll((unsigned long long)it) - 1;
            kw |= 1ull << b;
            uint64_t db = __shfl(diag, b);
            it &= ~db; cand &= ~db;
            it &= ~(1ull << b);
        }
        kw |= cand & nulls;
        int g  = lane >> 3;
        int wp = lane & 7;
        uint64_t acc = 0;
        if (wp >= w && wp < nw) {
            uint64_t mybits = kw & (0xFFull << (g * 8));
            while (mybits) {
                int b = __ffsll((unsigned long long)mybits) - 1;
                mybits &= mybits - 1;
                acc |= mask_s[wp * CAP + ((w << 6) + b)];
            }
        }
        acc |= __shfl_xor(acc, 8);
        acc |= __shfl_xor(acc, 16);
        acc |= __shfl_xor(acc, 32);
        if (lane < MW) removed |= acc;

        if (row < n && ((kw >> lane) & 1))
            dk[sg_s[row]] = 1.0f;
    }
}

// ONE block per class, 1024 threads (16 waves). Phase0 ballot-compaction
// bucket, rank-by-count sort, wave-task upper-triangle mask build, wave-0
// greedy scan. Float op order bit-identical to the passing pipeline.
__global__ __launch_bounds__(1024, 4) void nms_fused_kernel(
    const uint64_t* __restrict__ g_key, const float4* __restrict__ g_boxin,
    float* __restrict__ out)
{
    int c = blockIdx.x;
    int tid = threadIdx.x;

    __shared__ uint64_t key_s[CAP];          // 4 KB  (class-c keys, arrival order)
    __shared__ float4   boxu_s[CAP];         // 8 KB  (matching offset boxes)
    __shared__ float4   sbox_s[CAP + 64];    // 9 KB  (sorted, +64 sentinel pad)
    __shared__ int      sg_s[CAP];           // 2 KB  (sorted -> global pred idx)
    __shared__ uint64_t mask_s[MW * CAP];    // 32 KB (suppression bitmask)
    __shared__ int      ln_s;

    if (tid == 0) ln_s = 0;
    __syncthreads();

    // ---- phase 0: bucket class-c keys (12.3 vectorized iters/thread)
    {
        int lane = tid & 63;
        const ulonglong2* kp = (const ulonglong2*)g_key;
        for (int idx = tid; idx < NPRED / 2; idx += 1024) {
            ulonglong2 kv = kp[idx];
            bool m0 = (int)(kv.x >> 47) == c;
            bool m1 = (int)(kv.y >> 47) == c;
            unsigned long long b0 = __ballot(m0);
            unsigned long long b1 = __ballot(m1);
            int total = __popcll(b0) + __popcll(b1);
            int base = 0;
            if (lane == 0 && total) base = atomicAdd(&ln_s, total);
            base = __shfl(base, 0);
            unsigned long long lower = ((unsigned long long)1 << lane) - 1;
            int off0 = base + __popcll(b0 & lower);
            int off1 = base + __popcll(b0) + __popcll(b1 & lower);
            if (m0 && off0 < CAP) key_s[off0] = kv.x;
            if (m1 && off1 < CAP) key_s[off1] = kv.y;
        }
    }
    __syncthreads();
    int n = ln_s; if (n > CAP) n = CAP;
    if (n == 0) return;                       // uniform (all read ln_s)
    int nw = (n + 63) >> 6;

    // ---- phase 0b: gather boxes by g; sentinel-fill pad for the IoU loop
    for (int i = tid; i < n; i += 1024)
        boxu_s[i] = g_boxin[key_s[i] & 0x7FFF];
    for (int i = n + tid; i < n + 64; i += 1024)
        sbox_s[i] = make_float4(3e30f, 3e30f, 3e30f, 3e30f);
    __syncthreads();

    // ---- rank-by-count sort (keys unique: low 15 bits = global pred idx).
    // Ascending key == (score desc, g asc) == stable argsort(-score).
    for (int i0 = 0; i0 < n; i0 += 256) {
        int item = i0 + (tid >> 2);
        int sub  = tid & 3;
        bool act = item < n;
        int r = 0;
        uint64_t k = 0;
        if (act) {
            k = key_s[item];
            int nq = (n + 3) >> 2;
            int lo = sub * nq; if (lo > n) lo = n;
            int hi = lo + nq;  if (hi > n) hi = n;
            int jj = lo;
            for (; jj + 8 <= hi; jj += 8) {   // 8 independent b64 reads in flight
                int t0 = key_s[jj]   < k, t1 = key_s[jj+1] < k;
                int t2 = key_s[jj+2] < k, t3 = key_s[jj+3] < k;
                int t4 = key_s[jj+4] < k, t5 = key_s[jj+5] < k;
                int t6 = key_s[jj+6] < k, t7 = key_s[jj+7] < k;
                r += t0 + t1 + t2 + t3 + t4 + t5 + t6 + t7;
            }
            for (; jj < hi; jj++) r += (key_s[jj] < k);
        }
        r += __shfl_xor(r, 1);                // quad reduce (4 lanes/item)
        r += __shfl_xor(r, 2);
        if (act && sub == 0) {
            sbox_s[r] = boxu_s[item];
            sg_s[r]   = (int)(k & 0x7FFF);
        }
    }
    __syncthreads();

    // ---- mask build: upper-triangle words only, tiled as wave-tasks.
    {
        int wid   = tid >> 6;                 // 0..15
        int lane2 = tid & 63;
        int T = nw * (nw + 1) / 2;
        for (int t = wid; t < T; t += 16) {
            int w = 0, acc = 0;               // triangular decode (wave-uniform)
            while (t >= acc + w + 1) { acc += w + 1; w++; }
            int ib = t - acc;                 // 0..w
            int i  = (ib << 6) + lane2;       // <= n+62 (covered by pad)
            float4 b4 = sbox_s[i];
            float Ai = (b4.z - b4.x) * (b4.w - b4.y);
            int j0 = w << 6;
            uint64_t bits = 0;
#pragma unroll 8
            for (int jq = 0; jq < 64; jq++) {
                float4 bj = sbox_s[j0 + jq];   // LDS broadcast (pad => sentinel)
                float xx1 = fmaxf(b4.x, bj.x);
                float yy1 = fmaxf(b4.y, bj.y);
                float xx2 = fminf(b4.z, bj.z);
                float yy2 = fminf(b4.w, bj.w);
                float ww = fmaxf(1e-28f, xx2 - xx1);
                float hh = fmaxf(1e-28f, yy2 - yy1);
                float inter = ww * hh;
                float Aj = (bj.z - bj.x) * (bj.w - bj.y);
                float iou = inter / ((Ai + Aj) - inter);   // ref op order
                if ((j0 + jq) > i && iou > 0.6f) bits |= 1ull << jq;
            }
            if (i < n) mask_s[w * CAP + i] = bits;
        }
    }
    __syncthreads();

    // ---- greedy bitmask scan on wave 0 (== ref's fori_loop greedy NMS)
    if (tid >= 64) return;
    int lane = tid;
    uint64_t removed = 0;                      // lane L<8 holds word L
    for (int w = 0; w < nw; w++) {
        uint64_t rw = __shfl(removed, w);
        int row = (w << 6) + lane;
        uint64_t diag = (row < n) ? mask_s[w * CAP + row] : 0ull;
        int rem = n - (w << 6);
        uint64_t valid = (rem >= 64) ? ~0ull : ((1ull << rem) - 1ull);
        uint64_t nulls = __ballot(diag == 0ull);
        uint64_t cand = ~rw & valid;
        uint64_t kw = 0;
        uint64_t it = cand & ~nulls;           // rows with in-word forward bits
        while (it) {                           // uniform serial chain (rare rows)
            int b = __ffsll((unsigned long long)it) - 1;
            kw |= 1ull << b;
            uint64_t db = __shfl(diag, b);
            it &= ~db; cand &= ~db;
            it &= ~(1ull << b);
        }
        kw |= cand & nulls;                    // surviving zero-diag rows kept

        int g  = lane >> 3;
        int wp = lane & 7;
        uint64_t acc = 0;
        if (wp >= w && wp < nw) {
            uint64_t mybits = kw & (0xFFull << (g * 8));
            while (mybits) {
                int b = __ffsll((unsigned long long)mybits) - 1;
                mybits &= mybits - 1;
                acc |= mask_s[wp * CAP + ((w << 6) + b)];
            }
        }
        acc |= __shfl_xor(acc, 8);
        acc |= __shfl_xor(acc, 16);
        acc |= __shfl_xor(acc, 32);
        if (lane < MW) removed |= acc;

        if (row < n && ((kw >> lane) & 1))
            out[(size_t)sg_s[row] * 7 + 6] = 1.0f;
    }
}

extern "C" void kernel_launch(void* const* d_in, const int* in_sizes, int n_in,
                              void* d_out, int out_size, void* d_ws, size_t ws_size,
                              hipStream_t stream) {
    const float* ps = (const float*)d_in[0];
    const float* pm = (const float*)d_in[1];
    const float* pl = (const float*)d_in[2];
    float* out = (float*)d_out;

    char* ws = (char*)d_ws;
    float4*   g_boxin = (float4*)ws;                       // 403,200 B (dense by g)
    uint64_t* g_key   = (uint64_t*)(ws + 409600);          // 201,600 B (dense by g)
    float*    dummy   = (float*)(ws + 614400);             // 128 KB probe scratch

    decode_kernel<<<dim3(NCHUNK, 3), 64, 0, stream>>>(ps, pm, pl, out, g_boxin, g_key);
    // diagnostic ablation ladder (writes only to scratch; rocprof per-dispatch
    // durations attribute the fused kernel's time across phases)
    nms_probe_kernel<<<NCLS, 1024, 0, stream>>>(g_key, g_boxin, dummy, -1);
    nms_probe_kernel<<<NCLS, 1024, 0, stream>>>(g_key, g_boxin, dummy, 0);
    nms_probe_kernel<<<NCLS, 1024, 0, stream>>>(g_key, g_boxin, dummy, 1);
    nms_probe_kernel<<<NCLS, 1024, 0, stream>>>(g_key, g_boxin, dummy, 2);
    nms_probe_kernel<<<NCLS, 1024, 0, stream>>>(g_key, g_boxin, dummy, 3);
    // the real output-producing kernel (unchanged)
    nms_fused_kernel<<<NCLS, 1024, 0, stream>>>(g_key, g_boxin, out);
}

// Round 9
// 101.641 us; speedup vs baseline: 2.0134x; 2.0134x over previous
//
#include <hip/hip_runtime.h>
#include <cstdint>

#define NPRED 25200      // total predictions (8400 positions * 3 anchors)
#define NPOS  8400
#define NCLS  80
#define CAP   512        // max boxes per class (mean ~315, sigma ~18)
#define MW    8          // u64 mask words per row (512/64)
#define NCHUNK 132       // 64-position chunks: 100 (s0) + 25 (s1) + 7 (s2 tail)

__device__ __forceinline__ float sigmoidf_(float x) { return 1.0f / (1.0f + expf(-x)); }

// Block = (64-position chunk, anchor), 64 threads. REGISTER-RESIDENT class
// logits: per-class global loads are lane-contiguous (coalesced 256B/instr),
// so the former 20KB LDS transpose + 2 barriers + 160 latency-exposed LDS
// reads were pure overhead (R8 ablation: ~20us at 0.4 waves/SIMD). v[80]
// lives in VGPRs; (64,2) bounds cap at 256 VGPR -> no spill. Op order exact:
// fmax ascending, serial sum ascending, strict-> argmax ascending;
// best = beste/s*obj is the ref expression at the argmax (monotone map).
__global__ __launch_bounds__(64, 2) void decode_kernel(
    const float* __restrict__ ps, const float* __restrict__ pm, const float* __restrict__ pl,
    float* __restrict__ out,
    float4* __restrict__ g_boxin, uint64_t* __restrict__ g_key)
{
    int chunk = blockIdx.x;
    int a     = blockIdx.y;
    int t     = threadIdx.x;

    const float* p; int HW, W, base, si; float stride; int w0;
    if (chunk < 100)      { p = ps; HW = 6400; W = 80; stride = 8.f;  base = 0;    si = 0; w0 = chunk * 64; }
    else if (chunk < 125) { p = pm; HW = 1600; W = 40; stride = 16.f; base = 6400; si = 1; w0 = (chunk - 100) * 64; }
    else                  { p = pl; HW = 400;  W = 20; stride = 32.f; base = 8000; si = 2; w0 = (chunk - 125) * 64; }

    int local = w0 + t;
    bool valid = local < HW;
    int lclamp = valid ? local : (HW - 1);

    const float* cbase = p + (size_t)(3 + a * NCLS) * HW + lclamp;
    float v[NCLS];
#pragma unroll
    for (int c = 0; c < NCLS; c++) v[c] = cbase[(size_t)c * HW];

    float objl = p[(size_t)a * HW + lclamp];
    const float* rb = p + (size_t)(3 + 3 * NCLS + a * 4) * HW + lclamp;
    float tx = rb[0], ty = rb[(size_t)HW], tw = rb[(size_t)2 * HW], th = rb[(size_t)3 * HW];

    // pass A: max (ascending, order-exact)
    float m = -INFINITY;
#pragma unroll
    for (int c = 0; c < NCLS; c++) m = fmaxf(m, v[c]);
    // pass B: serial ascending sum + argmax of e (strict >, ascending)
    float s = 0.f; float beste = -1.f; int bi = 0;
#pragma unroll
    for (int c = 0; c < NCLS; c++) {
        float e = expf(v[c] - m);
        s += e;
        if (e > beste) { beste = e; bi = c; }
    }
    float obj = sigmoidf_(objl);
    float best = beste / s * obj;             // == ref's (e/s)*obj at argmax

    if (!valid) return;

    const float AW[9] = {10.f,16.f,33.f, 30.f,62.f,59.f, 116.f,156.f,373.f};
    const float AH[9] = {13.f,30.f,23.f, 61.f,45.f,119.f, 90.f,198.f,326.f};
    float aw = AW[si*3 + a], ah = AH[si*3 + a];

    int y = local / W;
    int x = local - y * W;
    float cx = (sigmoidf_(tx) + (float)x) * stride;
    float cy = (sigmoidf_(ty) + (float)y) * stride;
    float bw = expf(tw) * aw;
    float bh = expf(th) * ah;
    float x1 = fminf(fmaxf((cx - bw / 2.f) / 640.f, 0.f), 1.f);
    float y1 = fminf(fmaxf((cy - bh / 2.f) / 640.f, 0.f), 1.f);
    float x2 = fminf(fmaxf((cx + bw / 2.f) / 640.f, 0.f), 1.f);
    float y2 = fminf(fmaxf((cy + bh / 2.f) / 640.f, 0.f), 1.f);

    int g = (base + local) * 3 + a;           // reference global ordering
    float clsf = (float)bi;
    float* o = out + (size_t)g * 7;
    o[0] = x1; o[1] = y1; o[2] = x2; o[3] = y2;
    o[4] = best; o[5] = clsf; o[6] = 0.f;

    if (best >= 0.001f) {
        float off2 = clsf * 2.0f;             // ref IoU uses class-offset boxes
        g_boxin[g] = make_float4(x1 + off2, y1 + off2, x2 + off2, y2 + off2);
        unsigned u = __float_as_uint(best);
        u = (u & 0x80000000u) ? ~u : (u | 0x80000000u);
        g_key[g] = ((uint64_t)bi << 47) | ((uint64_t)(~u) << 15) | (uint64_t)g;
    } else {
        g_key[g] = (uint64_t)127 << 47;       // sentinel class: never matched
    }
}

// wave-level bucket step: ballot-compact 2 keys/thread; lane0-atomic valid
// because active lanes are always a tid-prefix within the wave.
#define BUCKET2(kv)                                                       \
    {                                                                     \
        bool m0 = (int)((kv).x >> 47) == c;                               \
        bool m1 = (int)((kv).y >> 47) == c;                               \
        unsigned long long b0 = __ballot(m0);                             \
        unsigned long long b1 = __ballot(m1);                             \
        int total = __popcll(b0) + __popcll(b1);                          \
        int bs = 0;                                                       \
        if (lane == 0 && total) bs = atomicAdd(&ln_s, total);             \
        bs = __shfl(bs, 0);                                               \
        unsigned long long lower = ((unsigned long long)1 << lane) - 1;   \
        int off0 = bs + __popcll(b0 & lower);                             \
        int off1 = bs + __popcll(b0) + __popcll(b1 & lower);              \
        if (m0 && off0 < CAP) key_s[off0] = (kv).x;                       \
        if (m1 && off1 < CAP) key_s[off1] = (kv).y;                       \
    }

// ONE block per class, 1024 threads (16 waves). R8's probe ladder + the
// pinned VGPR_Count=20 showed every phase is a per-wave serial LDS/L2
// latency chain (the source-level 8-deep pipelines can't exist in 20 VGPRs).
// This version shortens the chains instead of fighting the allocator:
// phase0 strip-2 (two b128 global loads in flight), sort via ds_read_b128
// pairs (half the reads), build with 2-deep broadcast prefetch, scan fold
// as a fixed predicated 8-read unroll. Float op order bit-identical.
__global__ __launch_bounds__(1024, 4) void nms_fused_kernel(
    const uint64_t* __restrict__ g_key, const float4* __restrict__ g_boxin,
    float* __restrict__ out)
{
    int c = blockIdx.x;
    int tid = threadIdx.x;

    __shared__ alignas(16) uint64_t key_s[CAP];   // 4 KB (class-c keys)
    __shared__ float4   boxu_s[CAP];              // 8 KB (matching offset boxes)
    __shared__ float4   sbox_s[CAP + 64];         // 9 KB (sorted, +64 sentinel)
    __shared__ int      sg_s[CAP];                // 2 KB (sorted -> pred idx)
    __shared__ uint64_t mask_s[MW * CAP];         // 32 KB (suppression bitmask)
    __shared__ int      ln_s;

    if (tid == 0) ln_s = 0;
    __syncthreads();

    // ---- phase 0: bucket class-c keys; 6 full strip-2 rounds + prefix tail
    {
        int lane = tid & 63;
        const ulonglong2* kp = (const ulonglong2*)g_key;
        const int HALF = NPRED / 2;          // 12600
        const int R2 = HALF >> 11;           // 6 full 2048-item rounds
        for (int r = 0; r < R2; r++) {
            int i0 = (r << 11) + tid;        // in-bounds for ALL threads
            ulonglong2 ka = kp[i0];
            ulonglong2 kb = kp[i0 + 1024];   // both loads in flight
            BUCKET2(ka);
            BUCKET2(kb);
        }
        int ti = (R2 << 11) + tid;           // 12288 + tid (prefix-active)
        if (ti < HALF) {
            ulonglong2 ka = kp[ti];
            BUCKET2(ka);
        }
    }
    __syncthreads();
    int n = ln_s; if (n > CAP) n = CAP;
    if (n == 0) return;                       // uniform (all read ln_s)
    int nw = (n + 63) >> 6;

    // ---- phase 0b: gather boxes by g; sentinel-fill pad for the IoU loop
    for (int i = tid; i < n; i += 1024)
        boxu_s[i] = g_boxin[key_s[i] & 0x7FFF];
    for (int i = n + tid; i < n + 64; i += 1024)
        sbox_s[i] = make_float4(3e30f, 3e30f, 3e30f, 3e30f);
    __syncthreads();

    // ---- rank-by-count sort (keys unique: low 15 bits = global pred idx).
    // Even quarter-split so LDS reads are 16B-aligned ds_read_b128 pairs.
    // Ascending key == (score desc, g asc) == stable argsort(-score).
    for (int i0 = 0; i0 < n; i0 += 256) {
        int item = i0 + (tid >> 2);
        int sub  = tid & 3;
        bool act = item < n;
        int r = 0;
        uint64_t k = 0;
        if (act) {
            k = key_s[item];
            int nq = (((n + 3) >> 2) + 1) & ~1;    // even, >= ceil(n/4)
            int lo = sub * nq; if (lo > n) lo = n; // lo even (or == n)
            int hi = lo + nq;  if (hi > n) hi = n;
            int jj = lo;
            for (; jj + 8 <= hi; jj += 8) {        // 4x ds_read_b128 in flight
                ulonglong2 p0 = *(const ulonglong2*)&key_s[jj];
                ulonglong2 p1 = *(const ulonglong2*)&key_s[jj + 2];
                ulonglong2 p2 = *(const ulonglong2*)&key_s[jj + 4];
                ulonglong2 p3 = *(const ulonglong2*)&key_s[jj + 6];
                r += (p0.x < k) + (p0.y < k) + (p1.x < k) + (p1.y < k)
                   + (p2.x < k) + (p2.y < k) + (p3.x < k) + (p3.y < k);
            }
            for (; jj + 2 <= hi; jj += 2) {
                ulonglong2 p0 = *(const ulonglong2*)&key_s[jj];
                r += (p0.x < k) + (p0.y < k);
            }
            if (jj < hi) r += (key_s[jj] < k);
        }
        r += __shfl_xor(r, 1);                // quad reduce (4 lanes/item)
        r += __shfl_xor(r, 2);
        if (act && sub == 0) {
            sbox_s[r] = boxu_s[item];
            sg_s[r]   = (int)(k & 0x7FFF);
        }
    }
    __syncthreads();

    // ---- mask build: upper-triangle words only, tiled as wave-tasks.
    // 2-deep rotation: next broadcast box load issued before current IoU.
    {
        int wid   = tid >> 6;                 // 0..15
        int lane2 = tid & 63;
        int T = nw * (nw + 1) / 2;
        for (int t = wid; t < T; t += 16) {
            int w = 0, acc = 0;               // triangular decode (wave-uniform)
            while (t >= acc + w + 1) { acc += w + 1; w++; }
            int ib = t - acc;                 // 0..w
            int i  = (ib << 6) + lane2;       // <= n+62 (covered by pad)
            float4 b4 = sbox_s[i];
            float Ai = (b4.z - b4.x) * (b4.w - b4.y);
            int j0 = w << 6;
            float4 bjc = sbox_s[j0];
            uint64_t bits = 0;
#pragma unroll 8
            for (int jq = 0; jq < 64; jq++) {
                float4 bjn = sbox_s[j0 + ((jq + 1) & 63)];  // prefetch (wrap ok)
                float xx1 = fmaxf(b4.x, bjc.x);
                float yy1 = fmaxf(b4.y, bjc.y);
                float xx2 = fminf(b4.z, bjc.z);
                float yy2 = fminf(b4.w, bjc.w);
                float ww = fmaxf(1e-28f, xx2 - xx1);
                float hh = fmaxf(1e-28f, yy2 - yy1);
                float inter = ww * hh;
                float Aj = (bjc.z - bjc.x) * (bjc.w - bjc.y);
                float iou = inter / ((Ai + Aj) - inter);   // ref op order
                if ((j0 + jq) > i && iou > 0.6f) bits |= 1ull << jq;
                bjc = bjn;
            }
            if (i < n) mask_s[w * CAP + i] = bits;
        }
    }
    __syncthreads();

    // ---- greedy bitmask scan on wave 0 (== ref's fori_loop greedy NMS)
    if (tid >= 64) return;
    int lane = tid;
    uint64_t removed = 0;                      // lane L<8 holds word L
    for (int w = 0; w < nw; w++) {
        uint64_t rw = __shfl(removed, w);
        int row = (w << 6) + lane;
        uint64_t diag = (row < n) ? mask_s[w * CAP + row] : 0ull;
        int rem = n - (w << 6);
        uint64_t valid = (rem >= 64) ? ~0ull : ((1ull << rem) - 1ull);
        uint64_t nulls = __ballot(diag == 0ull);
        uint64_t cand = ~rw & valid;
        uint64_t kw = 0;
        uint64_t it = cand & ~nulls;           // rows with in-word forward bits
        while (it) {                           // uniform serial chain (rare rows)
            int b = __ffsll((unsigned long long)it) - 1;
            kw |= 1ull << b;
            uint64_t db = __shfl(diag, b);
            it &= ~db; cand &= ~db;
            it &= ~(1ull << b);
        }
        kw |= cand & nulls;                    // surviving zero-diag rows kept

        // cooperative fold: lane (g=lane>>3, wp=lane&7) ORs kept rows' word
        // wp over bit-range [8g,8g+8). Fixed predicated 8-read unroll: all
        // reads independent/in-flight; rows >= n read garbage but their kw
        // bits are provably 0 (kw subset of valid) -> discarded.
        int g  = lane >> 3;
        int wp = lane & 7;
        uint64_t acc = 0;
        if (wp >= w && wp < nw) {
            int rbase = (w << 6) + (g << 3);
#pragma unroll
            for (int bb = 0; bb < 8; bb++) {
                uint64_t mword = mask_s[wp * CAP + rbase + bb];
                if ((kw >> ((g << 3) + bb)) & 1) acc |= mword;
            }
        }
        acc |= __shfl_xor(acc, 8);
        acc |= __shfl_xor(acc, 16);
        acc |= __shfl_xor(acc, 32);
        if (lane < MW) removed |= acc;

        if (row < n && ((kw >> lane) & 1))
            out[(size_t)sg_s[row] * 7 + 6] = 1.0f;
    }
}

extern "C" void kernel_launch(void* const* d_in, const int* in_sizes, int n_in,
                              void* d_out, int out_size, void* d_ws, size_t ws_size,
                              hipStream_t stream) {
    const float* ps = (const float*)d_in[0];
    const float* pm = (const float*)d_in[1];
    const float* pl = (const float*)d_in[2];
    float* out = (float*)d_out;

    char* ws = (char*)d_ws;
    float4*   g_boxin = (float4*)ws;                       // 403,200 B (dense by g)
    uint64_t* g_key   = (uint64_t*)(ws + 409600);          // 201,600 B (dense by g)

    decode_kernel<<<dim3(NCHUNK, 3), 64, 0, stream>>>(ps, pm, pl, out, g_boxin, g_key);
    nms_fused_kernel<<<NCLS, 1024, 0, stream>>>(g_key, g_boxin, out);
}